// Round 6
// baseline (266.579 us; speedup 1.0000x reference)
//
#include <hip/hip_runtime.h>
#include <stdint.h>

#define NBOX 8192
#define NBLK 1024   // 4 blocks/CU x 256 CU: co-resident (LDS 4x32=128<=160 KB,
                    // launch_bounds(256,4) caps VGPR<=128 -> 16 waves/CU <= 32)

// ws layout: float4 sbox[8192] (128 KB) | uint32_t flags[256] (1 KB) | uint32_t cnt[2]

__device__ __forceinline__ void grid_barrier(uint32_t* cnt, int phase) {
    __syncthreads();
    if (threadIdx.x == 0) {
        __hip_atomic_fetch_add(&cnt[phase], 1u, __ATOMIC_ACQ_REL,
                               __HIP_MEMORY_SCOPE_AGENT);
        while (__hip_atomic_load(&cnt[phase], __ATOMIC_ACQUIRE,
                                 __HIP_MEMORY_SCOPE_AGENT) < (uint32_t)NBLK)
            __builtin_amdgcn_s_sleep(2);
    }
    __syncthreads();
}

// ---------------------------------------------------------------------------
// Single fused kernel: rank-sort | barrier | suppress | barrier | write.
// Phase 1: rank(e) = #{bits_i > bits_e} + #{i<e: bits_i == bits_e}
//   == jnp.argsort(-score) stable order (scores >= 0 -> bits monotone).
//   u32 keys in 32 KB LDS, 32 threads/element, uint4 reads.
// Phase 2: wave owns one jg (8 sorted rows, j-boxes loaded once) x 4 i-slices.
//   2-deep register load ring; branch-free conservative prefilter
//   inter > 0.4110*ia + 0.4110*ja (0.4110 < 0.7/1.7*(1-6e-7), union>=256
//   -> never misses a true fl(inter/union) > 0.7 hit); exact IEEE-f32
//   reference math (incl. division) only on the rare candidate path.
// Phase 3: masked float4 write.
// ---------------------------------------------------------------------------
__global__ __launch_bounds__(256, 4) void nms_fused_kernel(
    const float4* __restrict__ bbox, const uint32_t* __restrict__ scoreBits,
    float4* __restrict__ out, float4* __restrict__ sbox,
    uint32_t* __restrict__ flags, uint32_t* __restrict__ cnt)
{
    __shared__ uint32_t keys[NBOX];          // 32 KB
    const int tid = threadIdx.x;

    // ---------------- Phase 1: stable rank + scatter ----------------
    if (blockIdx.x == 0) flags[tid] = 0;     // 256 words
    #pragma unroll
    for (int s = 0; s < 8; ++s)
        ((uint4*)keys)[tid + s * 256] = ((const uint4*)scoreBits)[tid + s * 256];
    __syncthreads();

    {
        const int e = blockIdx.x * 8 + (tid >> 5);   // element owned by 32 threads
        const int p = tid & 31;
        const uint32_t m = keys[e];
        int r = 0;
        #pragma unroll 4
        for (int s = 0; s < 64; ++s) {
            uint4 kb = ((const uint4*)keys)[s * 32 + p];   // keys s*128+4p ..+3
            int ib = s * 128 + p * 4;
            r += (int)(kb.x > m) + (int)((kb.x == m) & (ib + 0 < e));
            r += (int)(kb.y > m) + (int)((kb.y == m) & (ib + 1 < e));
            r += (int)(kb.z > m) + (int)((kb.z == m) & (ib + 2 < e));
            r += (int)(kb.w > m) + (int)((kb.w == m) & (ib + 3 < e));
        }
        r += __shfl_down(r, 16, 32);
        r += __shfl_down(r, 8, 32);
        r += __shfl_down(r, 4, 32);
        r += __shfl_down(r, 2, 32);
        r += __shfl_down(r, 1, 32);
        if (p == 0) sbox[r] = bbox[e];        // unique rank, one dwordx4 store
    }

    grid_barrier(cnt, 0);

    // ---------------- Phase 2: suppression ----------------
    {
        const int lane = tid & 63;
        const int wave = (int)blockIdx.x * 4 + (tid >> 6);  // 0..4095
        const int jg   = wave & 1023;          // fixed j-group per wave
        const int is0  = wave >> 10;           // 0..3; slices is0, is0+4, +8, +12
        const int j0   = jg * 8;

        float jy1[8], jx1[8], jy2[8], jx2[8], ja[8], tk[8];
        #pragma unroll
        for (int k = 0; k < 8; ++k) {
            float4 b = sbox[j0 + k];
            jy1[k] = b.x; jx1[k] = b.y; jy2[k] = b.z; jx2[k] = b.w;
            ja[k] = (b.z - b.x) * (b.w - b.y);  // same fp op order as reference
            tk[k] = 0.4110f * ja[k];
        }

        uint32_t hit = 0;
        for (int is = is0; is < 16; is += 4) {
            const int s0 = is * 512;
            if (s0 >= j0 + 7) break;           // monotone in is
            int nfull = (j0 - s0) >> 6;
            if (nfull > 8) nfull = 8;
            const int pc = nfull;
            const bool partial = (pc < 8) && (s0 + pc * 64 < j0 + 7);

            // all indices: 64-aligned base <= j0 <= 8184 -> <= 8128 -> +lane <= 8191
            float4 A = sbox[s0 + lane];
            float4 B = sbox[s0 + (pc > 0 ? 64 : 0) + lane];

            for (int c = 0; c < nfull; ++c) {
                int nidx = c + 2; if (nidx > pc) nidx = pc;
                float4 N = sbox[s0 + nidx * 64 + lane];

                const float iy1 = A.x, ix1 = A.y, iy2 = A.z, ix2 = A.w;
                const float ia  = (iy2 - iy1) * (ix2 - ix1);
                const float tia = 0.4110f * ia;

                int cand = 0;
                #pragma unroll
                for (int k = 0; k < 8; ++k) {
                    float ty1 = fmaxf(iy1, jy1[k]);
                    float tx1 = fmaxf(ix1, jx1[k]);
                    float ty2 = fminf(iy2, jy2[k]);
                    float tx2 = fminf(ix2, jx2[k]);
                    float ih = fmaxf(ty2 - ty1, 0.0f);
                    float iw = fmaxf(tx2 - tx1, 0.0f);
                    float inter = ih * iw;
                    cand |= __any(inter > tia + tk[k]);
                }
                if (cand) {                    // rare: exact reference math
                    #pragma unroll
                    for (int k = 0; k < 8; ++k) {
                        float ty1 = fmaxf(iy1, jy1[k]);
                        float tx1 = fmaxf(ix1, jx1[k]);
                        float ty2 = fminf(iy2, jy2[k]);
                        float tx2 = fminf(ix2, jx2[k]);
                        float ih = fmaxf(ty2 - ty1, 0.0f);
                        float iw = fmaxf(tx2 - tx1, 0.0f);
                        float inter = ih * iw;
                        float su  = ia + ja[k];
                        float un  = su - inter;     // fl(fl(ai+aj)-inter), as ref
                        float iou = inter / fmaxf(un, 1e-9f);
                        if (iou > 0.7f) hit |= (1u << k);
                    }
                }
                A = B; B = N;
            }

            if (partial) {                     // A holds chunk pc
                const int i = s0 + pc * 64 + lane;
                const float iy1 = A.x, ix1 = A.y, iy2 = A.z, ix2 = A.w;
                const float ia  = (iy2 - iy1) * (ix2 - ix1);
                const float tia = 0.4110f * ia;

                int cand = 0;
                #pragma unroll
                for (int k = 0; k < 8; ++k) {
                    float ty1 = fmaxf(iy1, jy1[k]);
                    float tx1 = fmaxf(ix1, jx1[k]);
                    float ty2 = fminf(iy2, jy2[k]);
                    float tx2 = fminf(ix2, jx2[k]);
                    float ih = fmaxf(ty2 - ty1, 0.0f);
                    float iw = fmaxf(tx2 - tx1, 0.0f);
                    float inter = ih * iw;
                    cand |= __any((i < j0 + k) & (inter > tia + tk[k]));
                }
                if (cand) {
                    #pragma unroll
                    for (int k = 0; k < 8; ++k) {
                        float ty1 = fmaxf(iy1, jy1[k]);
                        float tx1 = fmaxf(ix1, jx1[k]);
                        float ty2 = fminf(iy2, jy2[k]);
                        float tx2 = fminf(ix2, jx2[k]);
                        float ih = fmaxf(ty2 - ty1, 0.0f);
                        float iw = fmaxf(tx2 - tx1, 0.0f);
                        float inter = ih * iw;
                        float su  = ia + ja[k];
                        float un  = su - inter;
                        float iou = inter / fmaxf(un, 1e-9f);
                        if ((i < j0 + k) & (iou > 0.7f)) hit |= (1u << k);
                    }
                }
            }
        }

        uint32_t byte = 0;
        #pragma unroll
        for (int k = 0; k < 8; ++k)
            if (__any(hit & (1u << k))) byte |= (1u << k);
        if (lane == 0 && byte)
            atomicOr(&flags[jg >> 2], byte << ((jg & 3) * 8));
    }

    grid_barrier(cnt, 1);

    // ---------------- Phase 3: masked write ----------------
    {
        int j = (int)blockIdx.x * 256 + tid;   // blocks 0..31 do the writes
        if (j < NBOX) {
            bool sup = (flags[j >> 5] >> (j & 31)) & 1u;
            float4 v = sbox[j];
            if (sup) { v.x = 0.0f; v.y = 0.0f; v.z = 0.0f; v.w = 0.0f; }
            out[j] = v;
        }
    }
}

extern "C" void kernel_launch(void* const* d_in, const int* in_sizes, int n_in,
                              void* d_out, int out_size, void* d_ws, size_t ws_size,
                              hipStream_t stream) {
    const float4*   bbox  = (const float4*)d_in[0];    // (8192,4) f32
    const uint32_t* sbits = (const uint32_t*)d_in[1];  // (8192,)  f32 bits
    float4* out = (float4*)d_out;                      // (8192,4) f32
    float4* sbox = (float4*)d_ws;                      // 128 KB
    uint32_t* flags = (uint32_t*)((char*)d_ws + NBOX * 16);  // 1 KB
    uint32_t* cnt = flags + 256;                       // 2 barrier counters

    hipMemsetAsync(cnt, 0, 2 * sizeof(uint32_t), stream);
    hipLaunchKernelGGL(nms_fused_kernel, dim3(NBLK), dim3(256), 0, stream,
                       bbox, sbits, out, sbox, flags, cnt);
}

// Round 7
// 45.162 us; speedup vs baseline: 5.9027x; 5.9027x over previous
//
#include <hip/hip_runtime.h>
#include <stdint.h>

#define NBOX 8192

// ws layout: float4 sbox[8192] (128 KB) then uint32_t flags[256] (1 KB).

// ---------------------------------------------------------------------------
// Kernel 1: stable rank by (desc score, asc index); scatter boxes as float4
// into sorted order; block 0 zeroes the suppress-flag bitmap.
// rank(e) = #{i: bits_i > bits_e} + #{i < e: bits_i == bits_e}
//   == jnp.argsort(-score) stable order (scores >= 0 -> bits monotone).
// ---------------------------------------------------------------------------
__global__ __launch_bounds__(256) void nms_rank_kernel(
    const float4* __restrict__ bbox, const uint32_t* __restrict__ scoreBits,
    float4* __restrict__ sbox, uint32_t* __restrict__ flags)
{
    __shared__ uint32_t keys[NBOX];          // 32 KB
    const int t = threadIdx.x;
    if (blockIdx.x == 0) flags[t] = 0;       // 256 words

    #pragma unroll
    for (int s = 0; s < 8; ++s)              // 8 x uint4 = 8192 keys
        ((uint4*)keys)[t + s * 256] = ((const uint4*)scoreBits)[t + s * 256];
    __syncthreads();

    const int e = blockIdx.x * 16 + (t >> 4);  // element owned by 16 threads
    const int p = t & 15;
    const uint32_t m = keys[e];
    int cnt = 0;
    #pragma unroll 4
    for (int s = 0; s < 128; ++s) {
        uint4 kb = ((const uint4*)keys)[s * 16 + p];   // keys 64s+4p .. +3
        int ib = s * 64 + p * 4;
        cnt += (int)(kb.x > m) + (int)((kb.x == m) & (ib + 0 < e));
        cnt += (int)(kb.y > m) + (int)((kb.y == m) & (ib + 1 < e));
        cnt += (int)(kb.z > m) + (int)((kb.z == m) & (ib + 2 < e));
        cnt += (int)(kb.w > m) + (int)((kb.w == m) & (ib + 3 < e));
    }
    cnt += __shfl_down(cnt, 8, 16);
    cnt += __shfl_down(cnt, 4, 16);
    cnt += __shfl_down(cnt, 2, 16);
    cnt += __shfl_down(cnt, 1, 16);

    if (p == 0) sbox[cnt] = bbox[e];           // unique rank, one dwordx4 store
}

// ---------------------------------------------------------------------------
// Kernel 2: suppression, N-body style. 1 thread = 1 sorted row j (box held in
// registers); block stages a 128-box i-tile + areas into LDS once; inner loop
// reads LDS broadcasts only — no global loads, no cross-lane ops, no branches.
//
// Exactness, branch-free: reference computes iou = fl(inter / fl(max(un,1e-9)))
// and tests iou > 0.7f.  Here un >= ~200 always (inter <= min(ai,aj) under
// monotone fl ops; areas >= 256), so max() is identity.  fl division is
// monotone; with c = 0.7f (odd mantissa), fl(q) > c  <=>  q >= c + 2^-25
// (tie rounds to even = up).  So test (double)inter >= MD * (double)un with
// MD = (double)0.7f + 2^-25: MD has 25 bits, un 24 -> product exact in f64,
// comparison exact.  __f*_rn intrinsics block -ffp-contract=fast from fusing
// the value-sensitive chain into fmas.
//
// Grid: 32 j-blocks (256 rows) x 2(jb+1) i-tiles of 128 = 1056 uniform blocks.
// Tiles t >= 2*jb straddle the diagonal -> masked variant (i < j).
// ---------------------------------------------------------------------------
__device__ __forceinline__ bool iou_hit(float4 bi, float ia,
                                        float jy1, float jx1, float jy2,
                                        float jx2, float ja) {
    const double MD = (double)0.7f + 0x1.0p-25;
    float ty1 = fmaxf(bi.x, jy1);
    float tx1 = fmaxf(bi.y, jx1);
    float ty2 = fminf(bi.z, jy2);
    float tx2 = fminf(bi.w, jx2);
    float ih = fmaxf(__fsub_rn(ty2, ty1), 0.0f);
    float iw = fmaxf(__fsub_rn(tx2, tx1), 0.0f);
    float inter = __fmul_rn(ih, iw);
    float s  = __fadd_rn(ia, ja);
    float un = __fsub_rn(s, inter);       // == fl(fl(ai+aj)-inter); >= ~200
    return (double)inter >= MD * (double)un;
}

__global__ __launch_bounds__(256, 4) void nms_suppress_kernel(
    const float4* __restrict__ sbox, uint32_t* __restrict__ flags)
{
    __shared__ float4 LB[128];               // i-tile boxes   (2 KB)
    __shared__ float  LA[128];               // i-tile areas   (0.5 KB)
    const int tid = threadIdx.x;
    const int b = (int)blockIdx.x;           // 0..1055

    // jb = largest k with k(k+1) <= b  (cum blocks before jb = jb*(jb+1))
    int jb = (int)((sqrtf(4.0f * (float)b + 1.0f) - 1.0f) * 0.5f);
    while ((jb + 1) * (jb + 2) <= b) ++jb;
    while (jb * (jb + 1) > b) --jb;
    const int t = b - jb * (jb + 1);         // i-tile index, 0..2*jb+1
    const int ibase = t * 128;               // <= 256*jb+128 <= 8064
    const int j = jb * 256 + tid;            // this thread's sorted row

    if (tid < 128) {
        float4 bx = sbox[ibase + tid];
        LB[tid] = bx;
        LA[tid] = __fmul_rn(__fsub_rn(bx.z, bx.x), __fsub_rn(bx.w, bx.y));
    }
    float4 bj = sbox[j];
    const float jy1 = bj.x, jx1 = bj.y, jy2 = bj.z, jx2 = bj.w;
    const float ja = __fmul_rn(__fsub_rn(bj.z, bj.x), __fsub_rn(bj.w, bj.y));
    __syncthreads();

    bool supp = false;
    if (t < 2 * jb) {                        // all 128 i's < j for every thread
        #pragma unroll 4
        for (int ii = 0; ii < 128; ++ii)
            supp |= iou_hit(LB[ii], LA[ii], jy1, jx1, jy2, jx2, ja);
    } else {                                 // diagonal tile: mask i < j
        #pragma unroll 4
        for (int ii = 0; ii < 128; ++ii) {
            bool ok = (ibase + ii) < j;
            supp |= ok & iou_hit(LB[ii], LA[ii], jy1, jx1, jy2, jx2, ja);
        }
    }

    if (supp) atomicOr(&flags[j >> 5], 1u << (j & 31));
}

// ---------------------------------------------------------------------------
// Kernel 3: masked float4 write of sorted boxes.
// ---------------------------------------------------------------------------
__global__ __launch_bounds__(256) void nms_write_kernel(
    const float4* __restrict__ sbox, const uint32_t* __restrict__ flags,
    float4* __restrict__ out)
{
    int j = blockIdx.x * 256 + threadIdx.x;
    bool sup = (flags[j >> 5] >> (j & 31)) & 1u;
    float4 v = sbox[j];
    if (sup) { v.x = 0.0f; v.y = 0.0f; v.z = 0.0f; v.w = 0.0f; }
    out[j] = v;
}

extern "C" void kernel_launch(void* const* d_in, const int* in_sizes, int n_in,
                              void* d_out, int out_size, void* d_ws, size_t ws_size,
                              hipStream_t stream) {
    const float4*   bbox  = (const float4*)d_in[0];    // (8192,4) f32
    const uint32_t* sbits = (const uint32_t*)d_in[1];  // (8192,)  f32 bits
    float4* out = (float4*)d_out;                      // (8192,4) f32
    float4* sbox = (float4*)d_ws;                      // 128 KB
    uint32_t* flags = (uint32_t*)((char*)d_ws + NBOX * 16);  // 1 KB

    hipLaunchKernelGGL(nms_rank_kernel, dim3(NBOX / 16), dim3(256), 0, stream,
                       bbox, sbits, sbox, flags);
    // triangular tile grid: sum_{jb=0}^{31} 2*(jb+1) = 1056 uniform blocks
    hipLaunchKernelGGL(nms_suppress_kernel, dim3(1056), dim3(256), 0, stream,
                       sbox, flags);
    hipLaunchKernelGGL(nms_write_kernel, dim3(NBOX / 256), dim3(256), 0, stream,
                       sbox, flags, out);
}